// Round 10
// baseline (328.350 us; speedup 1.0000x reference)
//
#include <hip/hip_runtime.h>
#include <hip/hip_bf16.h>

// GraphSAGE 2-layer + mean-pool + linear head, MI355X (gfx950).
// Dtypes (R0-R5 forensics): floats fp32, indices int32, out fp32.
// R6 CSR-gather 1243us | R7 MFMA 757 | R8 LDS-W 593 | R9 XCD-fill 537 |
// R10 fp8 tables 517 | R11 MLP gather 438 | R12 k_cnt 359 | R13 nt-fill 356 |
// R14 work-queue REGRESSION | R15 fused fill+prep 345 | R16 336 |
// R17 nt-hints NEUTRAL | R18 atomic-pipeline NEUTRAL |
// R19 partition CSR build (atomic wall dead) 357 | R20 parallel fill 312 |
// R21 VALU-cut gather 298 | R22 32-edge batch REGRESSION 336 |
// R23 single-round batch 292 | R24 persistent waves NEUTRAL |
// R25 dual-node MLP ~neutral 288.8 -> gather pinned at random-128B-row
//     service wall (~156 rows/us/CU; TLP- and MLP-insensitive). Coop-phase
//     L2 sharding ruled out by arithmetic (52.8MB acc vs 40MB LDS -> >=8
//     grid syncs > upside); scatter-add = atomic fabric wall (R18/R19).
// R26: delete the col/deg global round-trip (60MB traffic + 1 launch).
//     Sub-buckets 128 nodes (SUBSH 7, NSUB 782, CAP 2432); k_fillgather
//     builds colL[128][48]+degL in LDS from its contiguous pe segment,
//     then 8 waves gather 16 nodes each (R25 dual-node body, heads from
//     LDS). col/deg/k_fill2 deleted; layer-2 pass re-reads pe (6.4MB).
//     ~4 blocks/CU x 8 waves = 32 waves/CU (same concurrency as before).

#define NN 100000
#define NE 1600000
#define DH 128
#define NG 512
#define CSTRIDE 48   // deg ~ Poisson(16); P(max>=48) ~ 5.6e-6, guarded anyway
#define NPREP 6250   // xconv blocks

#define SUBSH 7      // 128 nodes per sub-bucket
#define SUBN  128
#define NSUB  782    // ceil(NN / 128)
#define CAP   2432   // segment capacity: mean 2048 + ~8.5 sigma; guarded
#define NSCAN 256    // edge-slice scan blocks
#define ESPS  6250   // NE / NSCAN edges per scan block

#define PSUM_SCALE  1048576.0f        // 2^20
#define PSUM_INV    (1.0f/1048576.0f)

typedef __hip_bfloat16 bf16;
typedef __bf16 bf16x8 __attribute__((ext_vector_type(8)));
typedef float  f32x4  __attribute__((ext_vector_type(4)));
typedef float  f32x2  __attribute__((ext_vector_type(2)));
typedef unsigned u32x2 __attribute__((ext_vector_type(2)));
typedef unsigned u32x4 __attribute__((ext_vector_type(4)));
typedef unsigned char u8;

__device__ __forceinline__ void bf8_to_f(uint4 q, float* w) {
    union { unsigned u; float f; } t;
    t.u = q.x << 16;          w[0] = t.f;
    t.u = q.x & 0xffff0000u;  w[1] = t.f;
    t.u = q.y << 16;          w[2] = t.f;
    t.u = q.y & 0xffff0000u;  w[3] = t.f;
    t.u = q.z << 16;          w[4] = t.f;
    t.u = q.z & 0xffff0000u;  w[5] = t.f;
    t.u = q.w << 16;          w[6] = t.f;
    t.u = q.w & 0xffff0000u;  w[7] = t.f;
}

// pack 4 floats -> 4 fp8 e4m3 bytes (HW, RNE)
__device__ __forceinline__ unsigned pack4_fp8(float a, float b, float c, float d) {
    int p = __builtin_amdgcn_cvt_pk_fp8_f32(a, b, 0, false);
    p = __builtin_amdgcn_cvt_pk_fp8_f32(c, d, p, true);
    return (unsigned)p;
}

// ------------------------------------------------------------ prep+count ----

// Blocks 0..NSCAN-1: per-slice dst histogram over NSUB sub-buckets (LDS).
// Blocks NSCAN..: x->fp8 (nt); first 256 also W->bf16; next 2 cnt; one more
// zeroes the fq dummy row NN (gather's maskless out-of-range target).
__global__ __launch_bounds__(256) void k_prep(
    const int* __restrict__ ei, int* __restrict__ ccnt,
    const float* __restrict__ x, u8* __restrict__ fq,
    const float* __restrict__ w0, const float* __restrict__ w1,
    const float* __restrict__ w2, const float* __restrict__ w3,
    bf16* __restrict__ wb,
    const int* __restrict__ batch, int* __restrict__ cnt)
{
    const int bid = blockIdx.x, tid = threadIdx.x;

    if (bid < NSCAN) {
        __shared__ int c[NSUB];
        for (int i = tid; i < NSUB; i += 256) c[i] = 0;
        __syncthreads();
        const int e0 = bid * ESPS;
        for (int e = e0 + tid; e < e0 + ESPS; e += 256) {
            int d = __builtin_nontemporal_load(ei + NE + e);
            atomicAdd(&c[d >> SUBSH], 1);          // LDS atomic
        }
        __syncthreads();
        for (int i = tid; i < NSUB; i += 256) ccnt[i * NSCAN + bid] = c[i];
        return;
    }

    const int pb = bid - NSCAN;                   // 0 .. NPREP-1
    {   // xconv: 8 elems/thread, nt (read-once stream)
        int g = pb * 256 + tid;                   // 0 .. 1599999
        const f32x4* s = (const f32x4*)(x + (size_t)g * 8);
        f32x4 u0 = __builtin_nontemporal_load(s);
        f32x4 u1 = __builtin_nontemporal_load(s + 1);
        u32x2 v;
        v[0] = pack4_fp8(u0[0], u0[1], u0[2], u0[3]);
        v[1] = pack4_fp8(u1[0], u1[1], u1[2], u1[3]);
        __builtin_nontemporal_store(v, (u32x2*)(fq + (size_t)g * 8));
    }
    if (pb < 256) {                               // wconv
        int gid = pb * 256 + tid;                 // 0 .. 65535
        int m = gid >> 14, i = gid & 16383;
        const float* src = (m == 0) ? w0 : (m == 1) ? w1 : (m == 2) ? w2 : w3;
        wb[gid] = __float2bfloat16(src[i]);
    } else if (pb < 258) {                        // cnt (sorted batch)
        int g = (pb - 256) * 256 + tid;
        if (g < NG) {
            int lo0 = 0, hi0 = NN, lo1 = 0, hi1 = NN;
            while (lo0 < hi0) { int m = (lo0 + hi0) >> 1; if (batch[m] < g)     lo0 = m + 1; else hi0 = m; }
            while (lo1 < hi1) { int m = (lo1 + hi1) >> 1; if (batch[m] < g + 1) lo1 = m + 1; else hi1 = m; }
            cnt[g] = lo1 - lo0;
        }
    } else if (pb == 258) {                       // dummy zero row
        if (tid < 8) {
            uint4 z = {0u, 0u, 0u, 0u};
            ((uint4*)(fq + (size_t)NN * DH))[tid] = z;
        }
    }
}

// -------------------------------------------------------------- rowscan ----

// Block g: exclusive prefix over its 256 slice-counts (LDS Hillis-Steele),
// writes bofs[g][s] and tot[g].
__global__ __launch_bounds__(256) void k_rowscan(
    const int* __restrict__ ccnt, int* __restrict__ bofs, int* __restrict__ tot)
{
    const int g = blockIdx.x, t = threadIdx.x;
    __shared__ int s[256];
    int v = ccnt[g * NSCAN + t];
    s[t] = v;
    __syncthreads();
    #pragma unroll
    for (int off = 1; off < 256; off <<= 1) {
        int tmp = (t >= off) ? s[t - off] : 0;
        __syncthreads();
        s[t] += tmp;
        __syncthreads();
    }
    bofs[g * NSCAN + t] = s[t] - v;   // exclusive prefix
    if (t == 255) tot[g] = s[255];
}

// -------------------------------------------------------------- scatter ----

// Block s: rank[g] = g*CAP + bofs[g][s], then scatter its edge slice into
// dst-partitioned packed pe[] via LDS rank counters. No device atomics.
__global__ __launch_bounds__(256) void k_scatter(
    const int* __restrict__ ei, const int* __restrict__ bofs,
    unsigned* __restrict__ pe)
{
    const int s = blockIdx.x, tid = threadIdx.x;
    __shared__ int rank[NSUB];
    for (int g = tid; g < NSUB; g += 256)
        rank[g] = g * CAP + bofs[g * NSCAN + s];
    __syncthreads();

    const int e0 = s * ESPS;
    for (int e = e0 + tid; e < e0 + ESPS; e += 256) {
        int d   = __builtin_nontemporal_load(ei + NE + e);
        int src = __builtin_nontemporal_load(ei + e);
        int g = d >> SUBSH;
        int pos = atomicAdd(&rank[g], 1);          // LDS atomic
        if (pos < (g + 1) * CAP)                   // CAP overflow guard
            pe[pos] = ((unsigned)(d & (SUBN - 1)) << 17) | (unsigned)src;
    }
}

// ---------------------------------------------------------- fill+gather ----

// Block g owns sub-bucket g (128 nodes): builds colL/degL in LDS from its
// contiguous pe segment (no global col/deg!), then 8 waves gather 16 nodes
// each with the R25 dual-node body (heads from LDS). Slots >= dg carry the
// dummy zero row NN; max shfl slot 47 < 64. qsub==0 lanes store node A,
// qsub==1 lanes store node B (all quarters hold full sums after reduce).
__global__ __launch_bounds__(512) void k_fillgather(
    const unsigned* __restrict__ pe, const int* __restrict__ tot,
    const u8* __restrict__ fq, bf16* __restrict__ agg)
{
    __shared__ int colL[SUBN][CSTRIDE];   // 24576 B
    __shared__ int degL[SUBN];

    const int g = blockIdx.x, tid = threadIdx.x;
    if (tid < SUBN) degL[tid] = 0;
    __syncthreads();

    // ---- fill phase: pe segment -> LDS CSR ----
    const int lo = g * CAP;
    const int n  = min(tot[g], CAP);
    for (int e = lo + tid; e < lo + n; e += 512) {
        unsigned p = pe[e];
        int src = (int)(p & 0x1FFFFu);
        int dl  = (int)(p >> 17);
        int pos = atomicAdd(&degL[dl], 1);         // LDS atomic
        if (pos < CSTRIDE) colL[dl][pos] = src;
    }
    __syncthreads();

    // ---- gather phase ----
    const int lane = tid & 63;
    const int wave = tid >> 6;         // 0..7
    const int qsub = lane >> 4;        // edge slot 0..3
    const int l4   = lane & 15;        // feature group: 8*l4 .. 8*l4+7
    const unsigned l8 = (unsigned)l4 * 8u;
    const int nb = g << SUBSH;

    #pragma unroll 1
    for (int i = 0; i < 8; ++i) {      // 8 dual-pairs = 16 nodes per wave
        const int ln = wave * 16 + i * 2;
        const int nA = nb + ln;

        int dgrA = degL[ln];
        int dgrB = degL[ln + 1];
        const int dgsA = __builtin_amdgcn_readfirstlane(dgrA);
        const int dgsB = __builtin_amdgcn_readfirstlane(dgrB);
        const int dgA = dgsA > CSTRIDE ? CSTRIDE : dgsA;
        const int dgB = dgsB > CSTRIDE ? CSTRIDE : dgsB;
        const int dgM = dgA > dgB ? dgA : dgB;
        int vidxA = (lane < dgA) ? colL[ln][lane] : NN;
        int vidxB = (lane < dgB) ? colL[ln + 1][lane] : NN;

        f32x2 aA0 = {0.f, 0.f}, aA1 = {0.f, 0.f}, aA2 = {0.f, 0.f}, aA3 = {0.f, 0.f};
        f32x2 aB0 = {0.f, 0.f}, aB1 = {0.f, 0.f}, aB2 = {0.f, 0.f}, aB3 = {0.f, 0.f};

        for (int e = 0; e < dgM; e += 16) {
            int sA0 = __shfl(vidxA, e + qsub,      64);
            int sA1 = __shfl(vidxA, e + 4 + qsub,  64);
            int sA2 = __shfl(vidxA, e + 8 + qsub,  64);
            int sA3 = __shfl(vidxA, e + 12 + qsub, 64);
            int sB0 = __shfl(vidxB, e + qsub,      64);
            int sB1 = __shfl(vidxB, e + 4 + qsub,  64);
            int sB2 = __shfl(vidxB, e + 8 + qsub,  64);
            int sB3 = __shfl(vidxB, e + 12 + qsub, 64);
            uint2 qA0 = *(const uint2*)(fq + (((unsigned)sA0 << 7) + l8));
            uint2 qA1 = *(const uint2*)(fq + (((unsigned)sA1 << 7) + l8));
            uint2 qA2 = *(const uint2*)(fq + (((unsigned)sA2 << 7) + l8));
            uint2 qA3 = *(const uint2*)(fq + (((unsigned)sA3 << 7) + l8));
            uint2 qB0 = *(const uint2*)(fq + (((unsigned)sB0 << 7) + l8));
            uint2 qB1 = *(const uint2*)(fq + (((unsigned)sB1 << 7) + l8));
            uint2 qB2 = *(const uint2*)(fq + (((unsigned)sB2 << 7) + l8));
            uint2 qB3 = *(const uint2*)(fq + (((unsigned)sB3 << 7) + l8));
            aA0 += __builtin_amdgcn_cvt_pk_f32_fp8((int)qA0.x, false);
            aA1 += __builtin_amdgcn_cvt_pk_f32_fp8((int)qA0.x, true);
            aA2 += __builtin_amdgcn_cvt_pk_f32_fp8((int)qA0.y, false);
            aA3 += __builtin_amdgcn_cvt_pk_f32_fp8((int)qA0.y, true);
            aA0 += __builtin_amdgcn_cvt_pk_f32_fp8((int)qA1.x, false);
            aA1 += __builtin_amdgcn_cvt_pk_f32_fp8((int)qA1.x, true);
            aA2 += __builtin_amdgcn_cvt_pk_f32_fp8((int)qA1.y, false);
            aA3 += __builtin_amdgcn_cvt_pk_f32_fp8((int)qA1.y, true);
            aA0 += __builtin_amdgcn_cvt_pk_f32_fp8((int)qA2.x, false);
            aA1 += __builtin_amdgcn_cvt_pk_f32_fp8((int)qA2.x, true);
            aA2 += __builtin_amdgcn_cvt_pk_f32_fp8((int)qA2.y, false);
            aA3 += __builtin_amdgcn_cvt_pk_f32_fp8((int)qA2.y, true);
            aA0 += __builtin_amdgcn_cvt_pk_f32_fp8((int)qA3.x, false);
            aA1 += __builtin_amdgcn_cvt_pk_f32_fp8((int)qA3.x, true);
            aA2 += __builtin_amdgcn_cvt_pk_f32_fp8((int)qA3.y, false);
            aA3 += __builtin_amdgcn_cvt_pk_f32_fp8((int)qA3.y, true);
            aB0 += __builtin_amdgcn_cvt_pk_f32_fp8((int)qB0.x, false);
            aB1 += __builtin_amdgcn_cvt_pk_f32_fp8((int)qB0.x, true);
            aB2 += __builtin_amdgcn_cvt_pk_f32_fp8((int)qB0.y, false);
            aB3 += __builtin_amdgcn_cvt_pk_f32_fp8((int)qB0.y, true);
            aB0 += __builtin_amdgcn_cvt_pk_f32_fp8((int)qB1.x, false);
            aB1 += __builtin_amdgcn_cvt_pk_f32_fp8((int)qB1.x, true);
            aB2 += __builtin_amdgcn_cvt_pk_f32_fp8((int)qB1.y, false);
            aB3 += __builtin_amdgcn_cvt_pk_f32_fp8((int)qB1.y, true);
            aB0 += __builtin_amdgcn_cvt_pk_f32_fp8((int)qB2.x, false);
            aB1 += __builtin_amdgcn_cvt_pk_f32_fp8((int)qB2.x, true);
            aB2 += __builtin_amdgcn_cvt_pk_f32_fp8((int)qB2.y, false);
            aB3 += __builtin_amdgcn_cvt_pk_f32_fp8((int)qB2.y, true);
            aB0 += __builtin_amdgcn_cvt_pk_f32_fp8((int)qB3.x, false);
            aB1 += __builtin_amdgcn_cvt_pk_f32_fp8((int)qB3.x, true);
            aB2 += __builtin_amdgcn_cvt_pk_f32_fp8((int)qB3.y, false);
            aB3 += __builtin_amdgcn_cvt_pk_f32_fp8((int)qB3.y, true);
        }

        float rA[8] = {aA0[0], aA0[1], aA1[0], aA1[1], aA2[0], aA2[1], aA3[0], aA3[1]};
        float rB[8] = {aB0[0], aB0[1], aB1[0], aB1[1], aB2[0], aB2[1], aB3[0], aB3[1]};
        #pragma unroll
        for (int k = 0; k < 8; ++k) {
            rA[k] += __shfl_xor(rA[k], 16, 64);
            rB[k] += __shfl_xor(rB[k], 16, 64);
            rA[k] += __shfl_xor(rA[k], 32, 64);
            rB[k] += __shfl_xor(rB[k], 32, 64);
        }

        if (qsub == 0) {
            if (nA < NN) {
                float di = 1.0f / fmaxf((float)dgsA, 1.0f);
                union { bf16 b[8]; u32x4 u; } pk;
                #pragma unroll
                for (int k = 0; k < 8; ++k) pk.b[k] = __float2bfloat16(rA[k] * di);
                __builtin_nontemporal_store(pk.u, (u32x4*)(agg + nA * DH + l4 * 8));
            }
        } else if (qsub == 1) {
            if (nA + 1 < NN) {
                float di = 1.0f / fmaxf((float)dgsB, 1.0f);
                union { bf16 b[8]; u32x4 u; } pk;
                #pragma unroll
                for (int k = 0; k < 8; ++k) pk.b[k] = __float2bfloat16(rB[k] * di);
                __builtin_nontemporal_store(pk.u, (u32x4*)(agg + (nA + 1) * DH + l4 * 8));
            }
        }
    }
}

// --------------------------------------------------------- MFMA layer ----

// out[n][f] = relu( agg[n].Wl[f] + bias[f] + xq[n].Wr[f] ), K=128 per half.
// A-operand for BOTH halves' row operands comes from bf16 agg / fp8 xq.
// In-place: block reads only its own tile rows of xq before the post-sync
// epilogue overwrites them (POOL=false writes h1q over xq).
#define WSTR 136   // LDS row stride (bf16): +8 pad -> 2-way conflict (free)

template <bool POOL>
__global__ __launch_bounds__(256, 4) void k_layer(
    const bf16* __restrict__ agg, const u8* __restrict__ xq,
    const bf16* __restrict__ Wlb, const bf16* __restrict__ Wrb,
    const float* __restrict__ bias,
    u8* __restrict__ outq, int* __restrict__ psum,
    const int* __restrict__ batch)
{
    __shared__ bf16 wl[128 * WSTR];   // 34816 B, reused as output staging
    __shared__ int  bb[128];

    const int tid  = threadIdx.x;
    const int wave = tid >> 6;
    const int lane = tid & 63;
    const int lm   = lane & 15;
    const int kg   = lane >> 4;
    const int base = blockIdx.x * 128;
    const int wbase = base + wave * 32;

    const int r0 = min(wbase + lm,      NN - 1);
    const int r1 = min(wbase + 16 + lm, NN - 1);

    if (POOL && tid < 128) bb[tid] = batch[min(base + tid, NN - 1)];

    // stage Wl
    {
        const int row = tid >> 1, half = tid & 1;
        const uint4* src = (const uint4*)(Wlb + row * DH + half * 64);
        uint4* dst = (uint4*)(wl + row * WSTR + half * 64);
        #pragma unroll
        for (int i = 0; i < 8; ++i) dst[i] = src[i];
    }
    __syncthreads();

    f32x4 acc[2][8];
    #pragma unroll
    for (int i = 0; i < 2; ++i)
        #pragma unroll
        for (int t = 0; t < 8; ++t)
            acc[i][t] = (f32x4){0.f, 0.f, 0.f, 0.f};

    // ---- half 1: agg . Wl(LDS) ----
    #pragma unroll
    for (int kc = 0; kc < 4; ++kc) {
        const int ko = kc * 32 + kg * 8;
        bf16x8 a0 = *(const bf16x8*)(agg + r0 * DH + ko);
        bf16x8 a1 = *(const bf16x8*)(agg + r1 * DH + ko);
        #pragma unroll
        for (int t = 0; t < 8; ++t) {
            bf16x8 b = *(const bf16x8*)(wl + (t * 16 + lm) * WSTR + ko);
            acc[0][t] = __builtin_amdgcn_mfma_f32_16x16x32_bf16(a0, b, acc[0][t], 0, 0, 0);
            acc[1][t] = __builtin_amdgcn_mfma_f32_16x16x32_bf16(a1, b, acc[1][t], 0, 0, 0);
        }
    }
    __syncthreads();

    // restage Wr
    {
        const int row = tid >> 1, half = tid & 1;
        const uint4* src = (const uint4*)(Wrb + row * DH + half * 64);
        uint4* dst = (uint4*)(wl + row * WSTR + half * 64);
        #pragma unroll
        for (int i = 0; i < 8; ++i) dst[i] = src[i];
    }
    __syncthreads();

    // ---- half 2: xq(fp8) . Wr(LDS) ----
    #pragma unroll
    for (int kc = 0; kc < 4; ++kc) {
        const int ko = kc * 32 + kg * 8;
        bf16x8 a0, a1;
        uint2 q0 = *(const uint2*)(xq + (size_t)r0 * DH + ko);
        uint2 q1 = *(const uint2*)(xq + (size_t)r1 * DH + ko);
        f32x2 c0 = __builtin_amdgcn_cvt_pk_f32_fp8((int)q0.x, false);
        f32x2 c1 = __builtin_amdgcn_cvt_pk_f32_fp8((int)q0.x, true);
        f32x2 c2 = __builtin_amdgcn_cvt_pk_f32_fp8((int)q0.y, false);
        f32x2 c3 = __builtin_amdgcn_cvt_pk_f32_fp8((int)q0.y, true);
        a0[0] = (__bf16)c0[0]; a0[1] = (__bf16)c0[1];
        a0[2] = (__bf16)c1[0]; a0[3] = (__bf16)c1[1];
        a0[4] = (__bf16)c2[0]; a0[5] = (__bf16)c2[1];
        a0[6] = (__bf16)c3[0]; a0[7] = (__bf16)c3[1];
        c0 = __builtin_amdgcn_cvt_pk_f32_fp8((int)q1.x, false);
        c1 = __builtin_amdgcn_cvt_pk_f32_fp8((int)q1.x, true);
        c2 = __builtin_amdgcn_cvt_pk_f32_fp8((int)q1.y, false);
        c3 = __builtin_amdgcn_cvt_pk_f32_fp8((int)q1.y, true);
        a1[0] = (__bf16)c0[0]; a1[1] = (__bf16)c0[1];
        a1[2] = (__bf16)c1[0]; a1[3] = (__bf16)c1[1];
        a1[4] = (__bf16)c2[0]; a1[5] = (__bf16)c2[1];
        a1[6] = (__bf16)c3[0]; a1[7] = (__bf16)c3[1];
        #pragma unroll
        for (int t = 0; t < 8; ++t) {
            bf16x8 b = *(const bf16x8*)(wl + (t * 16 + lm) * WSTR + ko);
            acc[0][t] = __builtin_amdgcn_mfma_f32_16x16x32_bf16(a0, b, acc[0][t], 0, 0, 0);
            acc[1][t] = __builtin_amdgcn_mfma_f32_16x16x32_bf16(a1, b, acc[1][t], 0, 0, 0);
        }
    }
    __syncthreads();   // all waves done reading wl -> safe to reuse

    // ---- epilogue: stage bias+relu'd outputs (bf16) row-major in LDS ----
    bf16* ob = wl;     // 128 x 128, stride 128 (32KB)
    const int quad = lane >> 4;
    #pragma unroll
    for (int i = 0; i < 2; ++i) {
        #pragma unroll
        for (int r = 0; r < 4; ++r) {
            const int lr = wave * 32 + i * 16 + quad * 4 + r;
            const int n  = base + lr;
            #pragma unroll
            for (int t = 0; t < 8; ++t) {
                const int f = t * 16 + lm;
                float v = fmaxf(acc[i][t][r] + bias[f], 0.f);
                if (POOL && n >= NN) v = 0.f;   // zero tail for pooling
                ob[lr * DH + f] = __float2bfloat16(v);
            }
        }
    }
    __syncthreads();

    if (!POOL) {
        // coalesced fp8 store: block tile is contiguous 16KB in outq
        uint2* d = (uint2*)(outq + (size_t)base * DH);
        #pragma unroll
        for (int i = 0; i < 8; ++i) {
            const int idx = i * 256 + tid;          // 8B units, 16 per row
            const int n = base + (idx >> 4);
            if (n < NN) {
                uint4 s = ((const uint4*)ob)[idx];  // 8 bf16
                float w[8];
                bf8_to_f(s, w);
                uint2 o;
                o.x = pack4_fp8(w[0], w[1], w[2], w[3]);
                o.y = pack4_fp8(w[4], w[5], w[6], w[7]);
                d[idx] = o;
            }
        }
    } else {
        // sorted-batch run-length pooling: thread = (col f, half h)
        const int f = tid & 127, h = tid >> 7;
        float rs = 0.f;
        int cur = bb[h * 64];
        #pragma unroll 8
        for (int r = 0; r < 64; ++r) {
            const int row = h * 64 + r;
            float v = __bfloat162float(ob[row * DH + f]);
            int b = bb[row];
            if (b != cur) {   // wave-uniform (depends only on row)
                atomicAdd(&psum[cur * DH + f], __float2int_rn(rs * PSUM_SCALE));
                rs = 0.f; cur = b;
            }
            rs += v;
        }
        atomicAdd(&psum[cur * DH + f], __float2int_rn(rs * PSUM_SCALE));
    }
}

// --------------------------------------------------------------- final ----

__global__ __launch_bounds__(256) void k_final(
    const int* __restrict__ psum, const int* __restrict__ cnt,
    const float* __restrict__ Wlin, const float* __restrict__ blin,
    float* __restrict__ out)
{
    int gid = blockIdx.x * 256 + threadIdx.x;
    if (gid >= NG * 4) return;
    int gph = gid >> 2, c = gid & 3;
    const int* p = psum + gph * DH;
    const float* w = Wlin + c * DH;
    float s = 0.f;
    #pragma unroll 8
    for (int k = 0; k < DH; ++k)
        s += (float)p[k] * w[k];
    float inv = 1.0f / fmaxf((float)cnt[gph], 1.0f);
    out[gid] = s * PSUM_INV * inv + blin[c];
}

extern "C" void kernel_launch(void* const* d_in, const int* in_sizes, int n_in,
                              void* d_out, int out_size, void* d_ws, size_t ws_size,
                              hipStream_t stream) {
    const float* x     = (const float*)d_in[0];
    const int*   ei    = (const int*)d_in[1];
    const int*   batch = (const int*)d_in[2];
    const float* W1l   = (const float*)d_in[3];
    const float* b1    = (const float*)d_in[4];
    const float* W1r   = (const float*)d_in[5];
    const float* W2l   = (const float*)d_in[6];
    const float* b2    = (const float*)d_in[7];
    const float* W2r   = (const float*)d_in[8];
    const float* Wlin  = (const float*)d_in[9];
    const float* blin  = (const float*)d_in[10];
    float* out = (float*)d_out;

    // ws layout (48.0MB, under proven 77.46MB). col/deg deleted (R26).
    // cnt:  512 int         @ 64          (2048)
    // psum: 512*128 int     @ 2112        (262144)
    // wb:   4*16384 bf16    @ 264256      (131072)
    // ccnt: 782*256 int     @ 395328      (800768)
    // bofs: 782*256 int     @ 1196096     (800768)
    // tot:  782 int (pad)   @ 1996864     (3200)
    // agg:  NN*128 bf16     @ 2000064     (25600000)
    // fq:   (NN+1)*128 fp8  @ 27600064    (12800128)  xq/h1q + dummy row NN
    // pe:   782*2432 u32    @ 40400192    (7607296)   packed (dl,src)
    char* base = (char*)d_ws;
    int*      cnt  = (int*)(base + 64);
    int*      psum = (int*)(base + 2112);
    bf16*     wb   = (bf16*)(base + 264256);
    int*      ccnt = (int*)(base + 395328);
    int*      bofs = (int*)(base + 1196096);
    int*      tot  = (int*)(base + 1996864);
    bf16*     agg  = (bf16*)(base + 2000064);
    u8*       fq   = (u8*)(base + 27600064);
    unsigned* pe   = (unsigned*)(base + 40400192);

    bf16* W1lb = wb;
    bf16* W1rb = wb + 16384;
    bf16* W2lb = wb + 32768;
    bf16* W2rb = wb + 49152;

    // zero psum only (cnt/wb/ccnt/tot fully written; degL/colL are LDS)
    hipMemsetAsync(base + 2112, 0, 262144, stream);

    k_prep<<<NSCAN + NPREP, 256, 0, stream>>>(
        ei, ccnt, x, fq, W1l, W1r, W2l, W2r, wb, batch, cnt);
    k_rowscan<<<NSUB, 256, 0, stream>>>(ccnt, bofs, tot);
    k_scatter<<<NSCAN, 256, 0, stream>>>(ei, bofs, pe);

    // layer 1: LDS-CSR fill + gather xq(fp8) -> agg(bf16), then MFMA -> h1q
    k_fillgather<<<NSUB, 512, 0, stream>>>(pe, tot, fq, agg);
    k_layer<false><<<(NN + 127) / 128, 256, 0, stream>>>(agg, fq, W1lb, W1rb, b1,
                                                         fq, nullptr, nullptr);

    // layer 2: refill LDS-CSR + gather h1q(fp8) -> agg, MFMA + pooling
    k_fillgather<<<NSUB, 512, 0, stream>>>(pe, tot, fq, agg);
    k_layer<true><<<(NN + 127) / 128, 256, 0, stream>>>(agg, fq, W2lb, W2rb, b2,
                                                        nullptr, psum, batch);

    k_final<<<8, 256, 0, stream>>>(psum, cnt, Wlin, blin, out);
}

// Round 11
// 288.400 us; speedup vs baseline: 1.1385x; 1.1385x over previous
//
#include <hip/hip_runtime.h>
#include <hip/hip_bf16.h>

// GraphSAGE 2-layer + mean-pool + linear head, MI355X (gfx950).
// Dtypes (R0-R5 forensics): floats fp32, indices int32, out fp32.
// R6 CSR-gather 1243us | R7 MFMA 757 | R8 LDS-W 593 | R9 XCD-fill 537 |
// R10 fp8 tables 517 | R11 MLP gather 438 | R12 k_cnt 359 | R13 nt-fill 356 |
// R14 work-queue REGRESSION | R15 fused fill+prep 345 | R16 336 |
// R17 nt-hints NEUTRAL | R18 atomic-pipeline NEUTRAL |
// R19 partition CSR build (atomic wall dead) 357 | R20 parallel fill 312 |
// R21 VALU-cut gather 298 | R22 32-edge batch REGRESSION 336 |
// R23 single-round batch 292 | R24 persistent waves NEUTRAL |
// R25 dual-node MLP 288.8 (best) | R26 LDS-CSR fusion REGRESSION 328:
//     FETCH 82.5->141.9MB + occupancy 64->41% -- gather throughput comes
//     from MANY resident requester waves (L2 merges duplicate row reqs);
//     trading occupancy for locality loses. Reverted.
// R27: R25 verbatim + nt-load on pe stream in k_fill2 (read-once; don't
//     churn L2). Gather is pinned at the random-128B-row service wall
//     (~5.4 TB/s effective): 2x205MB row reads ~= 76us irreducible.

#define NN 100000
#define NE 1600000
#define DH 128
#define NG 512
#define CSTRIDE 48   // deg ~ Poisson(16); P(max>=48) ~ 5.6e-6, guarded anyway
#define NPREP 6250   // xconv blocks

#define SUBSH 8      // 256 nodes per sub-bucket
#define SUBN  256
#define NSUB  391    // ceil(NN / 256)
#define CAP   4608   // segment capacity: mean 4092 + 8*64; overflow guarded
#define NSCAN 256    // edge-slice scan blocks
#define ESPS  6250   // NE / NSCAN edges per scan block
#define GBLK  2048   // persistent gather blocks (8/CU resident)

#define PSUM_SCALE  1048576.0f        // 2^20
#define PSUM_INV    (1.0f/1048576.0f)

typedef __hip_bfloat16 bf16;
typedef __bf16 bf16x8 __attribute__((ext_vector_type(8)));
typedef float  f32x4  __attribute__((ext_vector_type(4)));
typedef float  f32x2  __attribute__((ext_vector_type(2)));
typedef unsigned u32x2 __attribute__((ext_vector_type(2)));
typedef unsigned u32x4 __attribute__((ext_vector_type(4)));
typedef unsigned char u8;

__device__ __forceinline__ void bf8_to_f(uint4 q, float* w) {
    union { unsigned u; float f; } t;
    t.u = q.x << 16;          w[0] = t.f;
    t.u = q.x & 0xffff0000u;  w[1] = t.f;
    t.u = q.y << 16;          w[2] = t.f;
    t.u = q.y & 0xffff0000u;  w[3] = t.f;
    t.u = q.z << 16;          w[4] = t.f;
    t.u = q.z & 0xffff0000u;  w[5] = t.f;
    t.u = q.w << 16;          w[6] = t.f;
    t.u = q.w & 0xffff0000u;  w[7] = t.f;
}

// pack 4 floats -> 4 fp8 e4m3 bytes (HW, RNE)
__device__ __forceinline__ unsigned pack4_fp8(float a, float b, float c, float d) {
    int p = __builtin_amdgcn_cvt_pk_fp8_f32(a, b, 0, false);
    p = __builtin_amdgcn_cvt_pk_fp8_f32(c, d, p, true);
    return (unsigned)p;
}

// ------------------------------------------------------------ prep+count ----

// Blocks 0..NSCAN-1: per-slice dst histogram over NSUB sub-buckets (LDS).
// Blocks NSCAN..: x->fp8 (nt); first 256 also W->bf16; next 2 cnt; one more
// zeroes the fq dummy row NN (gather's maskless out-of-range target).
__global__ __launch_bounds__(256) void k_prep(
    const int* __restrict__ ei, int* __restrict__ ccnt,
    const float* __restrict__ x, u8* __restrict__ fq,
    const float* __restrict__ w0, const float* __restrict__ w1,
    const float* __restrict__ w2, const float* __restrict__ w3,
    bf16* __restrict__ wb,
    const int* __restrict__ batch, int* __restrict__ cnt)
{
    const int bid = blockIdx.x, tid = threadIdx.x;

    if (bid < NSCAN) {
        __shared__ int c[NSUB];
        for (int i = tid; i < NSUB; i += 256) c[i] = 0;
        __syncthreads();
        const int e0 = bid * ESPS;
        for (int e = e0 + tid; e < e0 + ESPS; e += 256) {
            int d = __builtin_nontemporal_load(ei + NE + e);
            atomicAdd(&c[d >> SUBSH], 1);          // LDS atomic
        }
        __syncthreads();
        for (int i = tid; i < NSUB; i += 256) ccnt[i * NSCAN + bid] = c[i];
        return;
    }

    const int pb = bid - NSCAN;                   // 0 .. NPREP-1
    {   // xconv: 8 elems/thread, nt (read-once stream)
        int g = pb * 256 + tid;                   // 0 .. 1599999
        const f32x4* s = (const f32x4*)(x + (size_t)g * 8);
        f32x4 u0 = __builtin_nontemporal_load(s);
        f32x4 u1 = __builtin_nontemporal_load(s + 1);
        u32x2 v;
        v[0] = pack4_fp8(u0[0], u0[1], u0[2], u0[3]);
        v[1] = pack4_fp8(u1[0], u1[1], u1[2], u1[3]);
        __builtin_nontemporal_store(v, (u32x2*)(fq + (size_t)g * 8));
    }
    if (pb < 256) {                               // wconv
        int gid = pb * 256 + tid;                 // 0 .. 65535
        int m = gid >> 14, i = gid & 16383;
        const float* src = (m == 0) ? w0 : (m == 1) ? w1 : (m == 2) ? w2 : w3;
        wb[gid] = __float2bfloat16(src[i]);
    } else if (pb < 258) {                        // cnt (sorted batch)
        int g = (pb - 256) * 256 + tid;
        if (g < NG) {
            int lo0 = 0, hi0 = NN, lo1 = 0, hi1 = NN;
            while (lo0 < hi0) { int m = (lo0 + hi0) >> 1; if (batch[m] < g)     lo0 = m + 1; else hi0 = m; }
            while (lo1 < hi1) { int m = (lo1 + hi1) >> 1; if (batch[m] < g + 1) lo1 = m + 1; else hi1 = m; }
            cnt[g] = lo1 - lo0;
        }
    } else if (pb == 258) {                       // dummy zero row
        if (tid < 8) {
            uint4 z = {0u, 0u, 0u, 0u};
            ((uint4*)(fq + (size_t)NN * DH))[tid] = z;
        }
    }
}

// -------------------------------------------------------------- rowscan ----

// Block g: exclusive prefix over its 256 slice-counts (LDS Hillis-Steele),
// writes bofs[g][s] and tot[g].
__global__ __launch_bounds__(256) void k_rowscan(
    const int* __restrict__ ccnt, int* __restrict__ bofs, int* __restrict__ tot)
{
    const int g = blockIdx.x, t = threadIdx.x;
    __shared__ int s[256];
    int v = ccnt[g * NSCAN + t];
    s[t] = v;
    __syncthreads();
    #pragma unroll
    for (int off = 1; off < 256; off <<= 1) {
        int tmp = (t >= off) ? s[t - off] : 0;
        __syncthreads();
        s[t] += tmp;
        __syncthreads();
    }
    bofs[g * NSCAN + t] = s[t] - v;   // exclusive prefix
    if (t == 255) tot[g] = s[255];
}

// -------------------------------------------------------------- scatter ----

// Block s: rank[g] = g*CAP + bofs[g][s], then scatter its edge slice into
// dst-partitioned packed pe[] via LDS rank counters. No device atomics.
__global__ __launch_bounds__(256) void k_scatter(
    const int* __restrict__ ei, const int* __restrict__ bofs,
    unsigned* __restrict__ pe)
{
    const int s = blockIdx.x, tid = threadIdx.x;
    __shared__ int rank[NSUB];
    for (int g = tid; g < NSUB; g += 256)
        rank[g] = g * CAP + bofs[g * NSCAN + s];
    __syncthreads();

    const int e0 = s * ESPS;
    for (int e = e0 + tid; e < e0 + ESPS; e += 256) {
        int d   = __builtin_nontemporal_load(ei + NE + e);
        int src = __builtin_nontemporal_load(ei + e);
        int g = d >> SUBSH;
        int pos = atomicAdd(&rank[g], 1);          // LDS atomic
        if (pos < (g + 1) * CAP)                   // CAP overflow guard
            pe[pos] = ((unsigned)(d & (SUBN - 1)) << 17) | (unsigned)src;
    }
}

// ----------------------------------------------------------------- fill ----

// Block g owns sub-bucket g (256 nodes): contiguous packed segment, LDS slot
// assignment (1 counter/thread), L2-local col stores; writes final deg.
__global__ __launch_bounds__(256) void k_fill2(
    const unsigned* __restrict__ pe, const int* __restrict__ tot,
    int* __restrict__ deg, int* __restrict__ col)
{
    const int g = blockIdx.x, tid = threadIdx.x;
    __shared__ int degL[SUBN];
    degL[tid] = 0;
    __syncthreads();

    const int lo = g * CAP;
    const int n  = min(tot[g], CAP);
    const int nb = g << SUBSH;
    for (int e = lo + tid; e < lo + n; e += 256) {
        unsigned p = __builtin_nontemporal_load(pe + e);   // read-once stream
        int src = (int)(p & 0x1FFFFu);
        int dl  = (int)(p >> 17);
        int pos = atomicAdd(&degL[dl], 1);         // LDS atomic
        if (pos < CSTRIDE) col[(nb + dl) * CSTRIDE + pos] = src;
    }
    __syncthreads();

    int node = nb + tid;
    if (node < NN) deg[node] = degL[tid];
}

// -------------------------------------------------------------- gather ----

// Gather-mean from fp8 rows (128B). Persistent waves, DUAL-node rounds:
// each wave owns pair (2w, 2w+1); both heads prefetched one round ahead;
// per e-batch both nodes' 4 row-loads issue together (8 loads in flight).
// Loop bound max(dgA,dgB) is wave-uniform; slots >= dg (either node) carry
// the dummy zero row NN (incl. lanes 48..63), max slot 47 < 64. qsub==0
// lanes store node A's row, qsub==1 lanes store node B's (all quarters hold
// the full sums after the xor-reduce).
__global__ __launch_bounds__(256) void k_gather(
    const int* __restrict__ deg, const int* __restrict__ col,
    const u8* __restrict__ fq, bf16* __restrict__ agg)
{
    const int lane = threadIdx.x & 63;
    const int qsub = lane >> 4;        // edge slot 0..3
    const int l4   = lane & 15;        // feature group: 8*l4 .. 8*l4+7
    const unsigned l8 = (unsigned)l4 * 8u;
    const int wid  = blockIdx.x * 4 + (threadIdx.x >> 6);   // 0..GBLK*4-1
    const int NSTR = GBLK * 4 * 2;     // node stride per round

    int nA = wid * 2;                  // even; partner nB = nA+1 (NN even)

    // heads for the first pair
    int dgrA = deg[nA];
    int dgrB = deg[nA + 1];
    int vrawA = (lane < CSTRIDE) ? col[nA * CSTRIDE + lane] : 0;
    int vrawB = (lane < CSTRIDE) ? col[(nA + 1) * CSTRIDE + lane] : 0;

    while (true) {
        // ---- prefetch next pair's heads (independent of current body) ----
        const int nN = nA + NSTR;
        const bool more = nN < NN;
        int dgrAN = 0, dgrBN = 0, vrawAN = 0, vrawBN = 0;
        if (more) {
            dgrAN = deg[nN];
            dgrBN = deg[nN + 1];
            vrawAN = (lane < CSTRIDE) ? col[nN * CSTRIDE + lane] : 0;
            vrawBN = (lane < CSTRIDE) ? col[(nN + 1) * CSTRIDE + lane] : 0;
        }

        // ---- process current pair ----
        const int dgsA = __builtin_amdgcn_readfirstlane(dgrA);
        const int dgsB = __builtin_amdgcn_readfirstlane(dgrB);
        const int dgA = dgsA > CSTRIDE ? CSTRIDE : dgsA;
        const int dgB = dgsB > CSTRIDE ? CSTRIDE : dgsB;
        const int dgM = dgA > dgB ? dgA : dgB;
        int vidxA = (lane < dgA) ? vrawA : NN;
        int vidxB = (lane < dgB) ? vrawB : NN;

        f32x2 aA0 = {0.f, 0.f}, aA1 = {0.f, 0.f}, aA2 = {0.f, 0.f}, aA3 = {0.f, 0.f};
        f32x2 aB0 = {0.f, 0.f}, aB1 = {0.f, 0.f}, aB2 = {0.f, 0.f}, aB3 = {0.f, 0.f};

        for (int e = 0; e < dgM; e += 16) {
            int sA0 = __shfl(vidxA, e + qsub,      64);
            int sA1 = __shfl(vidxA, e + 4 + qsub,  64);
            int sA2 = __shfl(vidxA, e + 8 + qsub,  64);
            int sA3 = __shfl(vidxA, e + 12 + qsub, 64);
            int sB0 = __shfl(vidxB, e + qsub,      64);
            int sB1 = __shfl(vidxB, e + 4 + qsub,  64);
            int sB2 = __shfl(vidxB, e + 8 + qsub,  64);
            int sB3 = __shfl(vidxB, e + 12 + qsub, 64);
            uint2 qA0 = *(const uint2*)(fq + (((unsigned)sA0 << 7) + l8));
            uint2 qA1 = *(const uint2*)(fq + (((unsigned)sA1 << 7) + l8));
            uint2 qA2 = *(const uint2*)(fq + (((unsigned)sA2 << 7) + l8));
            uint2 qA3 = *(const uint2*)(fq + (((unsigned)sA3 << 7) + l8));
            uint2 qB0 = *(const uint2*)(fq + (((unsigned)sB0 << 7) + l8));
            uint2 qB1 = *(const uint2*)(fq + (((unsigned)sB1 << 7) + l8));
            uint2 qB2 = *(const uint2*)(fq + (((unsigned)sB2 << 7) + l8));
            uint2 qB3 = *(const uint2*)(fq + (((unsigned)sB3 << 7) + l8));
            aA0 += __builtin_amdgcn_cvt_pk_f32_fp8((int)qA0.x, false);
            aA1 += __builtin_amdgcn_cvt_pk_f32_fp8((int)qA0.x, true);
            aA2 += __builtin_amdgcn_cvt_pk_f32_fp8((int)qA0.y, false);
            aA3 += __builtin_amdgcn_cvt_pk_f32_fp8((int)qA0.y, true);
            aA0 += __builtin_amdgcn_cvt_pk_f32_fp8((int)qA1.x, false);
            aA1 += __builtin_amdgcn_cvt_pk_f32_fp8((int)qA1.x, true);
            aA2 += __builtin_amdgcn_cvt_pk_f32_fp8((int)qA1.y, false);
            aA3 += __builtin_amdgcn_cvt_pk_f32_fp8((int)qA1.y, true);
            aA0 += __builtin_amdgcn_cvt_pk_f32_fp8((int)qA2.x, false);
            aA1 += __builtin_amdgcn_cvt_pk_f32_fp8((int)qA2.x, true);
            aA2 += __builtin_amdgcn_cvt_pk_f32_fp8((int)qA2.y, false);
            aA3 += __builtin_amdgcn_cvt_pk_f32_fp8((int)qA2.y, true);
            aA0 += __builtin_amdgcn_cvt_pk_f32_fp8((int)qA3.x, false);
            aA1 += __builtin_amdgcn_cvt_pk_f32_fp8((int)qA3.x, true);
            aA2 += __builtin_amdgcn_cvt_pk_f32_fp8((int)qA3.y, false);
            aA3 += __builtin_amdgcn_cvt_pk_f32_fp8((int)qA3.y, true);
            aB0 += __builtin_amdgcn_cvt_pk_f32_fp8((int)qB0.x, false);
            aB1 += __builtin_amdgcn_cvt_pk_f32_fp8((int)qB0.x, true);
            aB2 += __builtin_amdgcn_cvt_pk_f32_fp8((int)qB0.y, false);
            aB3 += __builtin_amdgcn_cvt_pk_f32_fp8((int)qB0.y, true);
            aB0 += __builtin_amdgcn_cvt_pk_f32_fp8((int)qB1.x, false);
            aB1 += __builtin_amdgcn_cvt_pk_f32_fp8((int)qB1.x, true);
            aB2 += __builtin_amdgcn_cvt_pk_f32_fp8((int)qB1.y, false);
            aB3 += __builtin_amdgcn_cvt_pk_f32_fp8((int)qB1.y, true);
            aB0 += __builtin_amdgcn_cvt_pk_f32_fp8((int)qB2.x, false);
            aB1 += __builtin_amdgcn_cvt_pk_f32_fp8((int)qB2.x, true);
            aB2 += __builtin_amdgcn_cvt_pk_f32_fp8((int)qB2.y, false);
            aB3 += __builtin_amdgcn_cvt_pk_f32_fp8((int)qB2.y, true);
            aB0 += __builtin_amdgcn_cvt_pk_f32_fp8((int)qB3.x, false);
            aB1 += __builtin_amdgcn_cvt_pk_f32_fp8((int)qB3.x, true);
            aB2 += __builtin_amdgcn_cvt_pk_f32_fp8((int)qB3.y, false);
            aB3 += __builtin_amdgcn_cvt_pk_f32_fp8((int)qB3.y, true);
        }

        float rA[8] = {aA0[0], aA0[1], aA1[0], aA1[1], aA2[0], aA2[1], aA3[0], aA3[1]};
        float rB[8] = {aB0[0], aB0[1], aB1[0], aB1[1], aB2[0], aB2[1], aB3[0], aB3[1]};
        #pragma unroll
        for (int i = 0; i < 8; ++i) {
            rA[i] += __shfl_xor(rA[i], 16, 64);
            rB[i] += __shfl_xor(rB[i], 16, 64);
            rA[i] += __shfl_xor(rA[i], 32, 64);
            rB[i] += __shfl_xor(rB[i], 32, 64);
        }

        if (qsub == 0) {
            float di = 1.0f / fmaxf((float)dgsA, 1.0f);
            union { bf16 b[8]; u32x4 u; } pk;
            #pragma unroll
            for (int i = 0; i < 8; ++i) pk.b[i] = __float2bfloat16(rA[i] * di);
            __builtin_nontemporal_store(pk.u, (u32x4*)(agg + nA * DH + l4 * 8));
        } else if (qsub == 1) {
            float di = 1.0f / fmaxf((float)dgsB, 1.0f);
            union { bf16 b[8]; u32x4 u; } pk;
            #pragma unroll
            for (int i = 0; i < 8; ++i) pk.b[i] = __float2bfloat16(rB[i] * di);
            __builtin_nontemporal_store(pk.u, (u32x4*)(agg + (nA + 1) * DH + l4 * 8));
        }

        if (!more) break;
        nA = nN;
        dgrA = dgrAN; dgrB = dgrBN; vrawA = vrawAN; vrawB = vrawBN;
    }
}

// --------------------------------------------------------- MFMA layer ----

// out[n][f] = relu( agg[n].Wl[f] + bias[f] + xq[n].Wr[f] ), K=128 per half.
// A-operand for BOTH halves' row operands comes from bf16 agg / fp8 xq.
// In-place: block reads only its own tile rows of xq before the post-sync
// epilogue overwrites them (POOL=false writes h1q over xq).
#define WSTR 136   // LDS row stride (bf16): +8 pad -> 2-way conflict (free)

template <bool POOL>
__global__ __launch_bounds__(256, 4) void k_layer(
    const bf16* __restrict__ agg, const u8* __restrict__ xq,
    const bf16* __restrict__ Wlb, const bf16* __restrict__ Wrb,
    const float* __restrict__ bias,
    u8* __restrict__ outq, int* __restrict__ psum,
    const int* __restrict__ batch)
{
    __shared__ bf16 wl[128 * WSTR];   // 34816 B, reused as output staging
    __shared__ int  bb[128];

    const int tid  = threadIdx.x;
    const int wave = tid >> 6;
    const int lane = tid & 63;
    const int lm   = lane & 15;
    const int kg   = lane >> 4;
    const int base = blockIdx.x * 128;
    const int wbase = base + wave * 32;

    const int r0 = min(wbase + lm,      NN - 1);
    const int r1 = min(wbase + 16 + lm, NN - 1);

    if (POOL && tid < 128) bb[tid] = batch[min(base + tid, NN - 1)];

    // stage Wl
    {
        const int row = tid >> 1, half = tid & 1;
        const uint4* src = (const uint4*)(Wlb + row * DH + half * 64);
        uint4* dst = (uint4*)(wl + row * WSTR + half * 64);
        #pragma unroll
        for (int i = 0; i < 8; ++i) dst[i] = src[i];
    }
    __syncthreads();

    f32x4 acc[2][8];
    #pragma unroll
    for (int i = 0; i < 2; ++i)
        #pragma unroll
        for (int t = 0; t < 8; ++t)
            acc[i][t] = (f32x4){0.f, 0.f, 0.f, 0.f};

    // ---- half 1: agg . Wl(LDS) ----
    #pragma unroll
    for (int kc = 0; kc < 4; ++kc) {
        const int ko = kc * 32 + kg * 8;
        bf16x8 a0 = *(const bf16x8*)(agg + r0 * DH + ko);
        bf16x8 a1 = *(const bf16x8*)(agg + r1 * DH + ko);
        #pragma unroll
        for (int t = 0; t < 8; ++t) {
            bf16x8 b = *(const bf16x8*)(wl + (t * 16 + lm) * WSTR + ko);
            acc[0][t] = __builtin_amdgcn_mfma_f32_16x16x32_bf16(a0, b, acc[0][t], 0, 0, 0);
            acc[1][t] = __builtin_amdgcn_mfma_f32_16x16x32_bf16(a1, b, acc[1][t], 0, 0, 0);
        }
    }
    __syncthreads();

    // restage Wr
    {
        const int row = tid >> 1, half = tid & 1;
        const uint4* src = (const uint4*)(Wrb + row * DH + half * 64);
        uint4* dst = (uint4*)(wl + row * WSTR + half * 64);
        #pragma unroll
        for (int i = 0; i < 8; ++i) dst[i] = src[i];
    }
    __syncthreads();

    // ---- half 2: xq(fp8) . Wr(LDS) ----
    #pragma unroll
    for (int kc = 0; kc < 4; ++kc) {
        const int ko = kc * 32 + kg * 8;
        bf16x8 a0, a1;
        uint2 q0 = *(const uint2*)(xq + (size_t)r0 * DH + ko);
        uint2 q1 = *(const uint2*)(xq + (size_t)r1 * DH + ko);
        f32x2 c0 = __builtin_amdgcn_cvt_pk_f32_fp8((int)q0.x, false);
        f32x2 c1 = __builtin_amdgcn_cvt_pk_f32_fp8((int)q0.x, true);
        f32x2 c2 = __builtin_amdgcn_cvt_pk_f32_fp8((int)q0.y, false);
        f32x2 c3 = __builtin_amdgcn_cvt_pk_f32_fp8((int)q0.y, true);
        a0[0] = (__bf16)c0[0]; a0[1] = (__bf16)c0[1];
        a0[2] = (__bf16)c1[0]; a0[3] = (__bf16)c1[1];
        a0[4] = (__bf16)c2[0]; a0[5] = (__bf16)c2[1];
        a0[6] = (__bf16)c3[0]; a0[7] = (__bf16)c3[1];
        c0 = __builtin_amdgcn_cvt_pk_f32_fp8((int)q1.x, false);
        c1 = __builtin_amdgcn_cvt_pk_f32_fp8((int)q1.x, true);
        c2 = __builtin_amdgcn_cvt_pk_f32_fp8((int)q1.y, false);
        c3 = __builtin_amdgcn_cvt_pk_f32_fp8((int)q1.y, true);
        a1[0] = (__bf16)c0[0]; a1[1] = (__bf16)c0[1];
        a1[2] = (__bf16)c1[0]; a1[3] = (__bf16)c1[1];
        a1[4] = (__bf16)c2[0]; a1[5] = (__bf16)c2[1];
        a1[6] = (__bf16)c3[0]; a1[7] = (__bf16)c3[1];
        #pragma unroll
        for (int t = 0; t < 8; ++t) {
            bf16x8 b = *(const bf16x8*)(wl + (t * 16 + lm) * WSTR + ko);
            acc[0][t] = __builtin_amdgcn_mfma_f32_16x16x32_bf16(a0, b, acc[0][t], 0, 0, 0);
            acc[1][t] = __builtin_amdgcn_mfma_f32_16x16x32_bf16(a1, b, acc[1][t], 0, 0, 0);
        }
    }
    __syncthreads();   // all waves done reading wl -> safe to reuse

    // ---- epilogue: stage bias+relu'd outputs (bf16) row-major in LDS ----
    bf16* ob = wl;     // 128 x 128, stride 128 (32KB)
    const int quad = lane >> 4;
    #pragma unroll
    for (int i = 0; i < 2; ++i) {
        #pragma unroll
        for (int r = 0; r < 4; ++r) {
            const int lr = wave * 32 + i * 16 + quad * 4 + r;
            const int n  = base + lr;
            #pragma unroll
            for (int t = 0; t < 8; ++t) {
                const int f = t * 16 + lm;
                float v = fmaxf(acc[i][t][r] + bias[f], 0.f);
                if (POOL && n >= NN) v = 0.f;   // zero tail for pooling
                ob[lr * DH + f] = __float2bfloat16(v);
            }
        }
    }
    __syncthreads();

    if (!POOL) {
        // coalesced fp8 store: block tile is contiguous 16KB in outq
        uint2* d = (uint2*)(outq + (size_t)base * DH);
        #pragma unroll
        for (int i = 0; i < 8; ++i) {
            const int idx = i * 256 + tid;          // 8B units, 16 per row
            const int n = base + (idx >> 4);
            if (n < NN) {
                uint4 s = ((const uint4*)ob)[idx];  // 8 bf16
                float w[8];
                bf8_to_f(s, w);
                uint2 o;
                o.x = pack4_fp8(w[0], w[1], w[2], w[3]);
                o.y = pack4_fp8(w[4], w[5], w[6], w[7]);
                d[idx] = o;
            }
        }
    } else {
        // sorted-batch run-length pooling: thread = (col f, half h)
        const int f = tid & 127, h = tid >> 7;
        float rs = 0.f;
        int cur = bb[h * 64];
        #pragma unroll 8
        for (int r = 0; r < 64; ++r) {
            const int row = h * 64 + r;
            float v = __bfloat162float(ob[row * DH + f]);
            int b = bb[row];
            if (b != cur) {   // wave-uniform (depends only on row)
                atomicAdd(&psum[cur * DH + f], __float2int_rn(rs * PSUM_SCALE));
                rs = 0.f; cur = b;
            }
            rs += v;
        }
        atomicAdd(&psum[cur * DH + f], __float2int_rn(rs * PSUM_SCALE));
    }
}

// --------------------------------------------------------------- final ----

__global__ __launch_bounds__(256) void k_final(
    const int* __restrict__ psum, const int* __restrict__ cnt,
    const float* __restrict__ Wlin, const float* __restrict__ blin,
    float* __restrict__ out)
{
    int gid = blockIdx.x * 256 + threadIdx.x;
    if (gid >= NG * 4) return;
    int gph = gid >> 2, c = gid & 3;
    const int* p = psum + gph * DH;
    const float* w = Wlin + c * DH;
    float s = 0.f;
    #pragma unroll 8
    for (int k = 0; k < DH; ++k)
        s += (float)p[k] * w[k];
    float inv = 1.0f / fmaxf((float)cnt[gph], 1.0f);
    out[gid] = s * PSUM_INV * inv + blin[c];
}

extern "C" void kernel_launch(void* const* d_in, const int* in_sizes, int n_in,
                              void* d_out, int out_size, void* d_ws, size_t ws_size,
                              hipStream_t stream) {
    const float* x     = (const float*)d_in[0];
    const int*   ei    = (const int*)d_in[1];
    const int*   batch = (const int*)d_in[2];
    const float* W1l   = (const float*)d_in[3];
    const float* b1    = (const float*)d_in[4];
    const float* W1r   = (const float*)d_in[5];
    const float* W2l   = (const float*)d_in[6];
    const float* b2    = (const float*)d_in[7];
    const float* W2r   = (const float*)d_in[8];
    const float* Wlin  = (const float*)d_in[9];
    const float* blin  = (const float*)d_in[10];
    float* out = (float*)d_out;

    // ws layout (66.4MB, under proven 77.46MB):
    // deg:  NN int          @ 64          (400000)
    // cnt:  512 int         @ 400064      (2048)
    // psum: 512*128 int     @ 402112      (262144)
    // wb:   4*16384 bf16    @ 664256      (131072)
    // ccnt: 391*256 int     @ 795328      (400384)
    // bofs: 391*256 int     @ 1195712     (400384)
    // tot:  391 int (pad)   @ 1596096     (1600)
    // col:  NN*48 int       @ 1597696     (19200000)
    // agg:  NN*128 bf16     @ 20797696    (25600000)
    // fq:   (NN+1)*128 fp8  @ 46397696    (12800128)  xq/h1q + dummy row NN
    // pe:   391*4608 u32    @ 59200000    (7206912)   packed (dl,src)
    char* base = (char*)d_ws;
    int*      deg  = (int*)(base + 64);
    int*      cnt  = (int*)(base + 400064);
    int*      psum = (int*)(base + 402112);
    bf16*     wb   = (bf16*)(base + 664256);
    int*      ccnt = (int*)(base + 795328);
    int*      bofs = (int*)(base + 1195712);
    int*      tot  = (int*)(base + 1596096);
    int*      col  = (int*)(base + 1597696);
    bf16*     agg  = (bf16*)(base + 20797696);
    u8*       fq   = (u8*)(base + 46397696);
    unsigned* pe   = (unsigned*)(base + 59200000);

    bf16* W1lb = wb;
    bf16* W1rb = wb + 16384;
    bf16* W2lb = wb + 32768;
    bf16* W2rb = wb + 49152;

    // zero psum only (deg written by k_fill2; cnt/wb/ccnt fully written)
    hipMemsetAsync(base + 402112, 0, 262144, stream);

    k_prep<<<NSCAN + NPREP, 256, 0, stream>>>(
        ei, ccnt, x, fq, W1l, W1r, W2l, W2r, wb, batch, cnt);
    k_rowscan<<<NSUB, 256, 0, stream>>>(ccnt, bofs, tot);
    k_scatter<<<NSCAN, 256, 0, stream>>>(ei, bofs, pe);
    k_fill2<<<NSUB, 256, 0, stream>>>(pe, tot, deg, col);

    // layer 1: gather xq(fp8) -> agg(bf16), MFMA GEMM -> h1q(fp8, over xq)
    k_gather<<<GBLK, 256, 0, stream>>>(deg, col, fq, agg);
    k_layer<false><<<(NN + 127) / 128, 256, 0, stream>>>(agg, fq, W1lb, W1rb, b1,
                                                         fq, nullptr, nullptr);

    // layer 2: gather h1q(fp8) -> agg(bf16), MFMA GEMM + pooling -> psum
    k_gather<<<GBLK, 256, 0, stream>>>(deg, col, fq, agg);
    k_layer<true><<<(NN + 127) / 128, 256, 0, stream>>>(agg, fq, W2lb, W2rb, b2,
                                                        nullptr, psum, batch);

    k_final<<<8, 256, 0, stream>>>(psum, cnt, Wlin, blin, out);
}